// Round 1
// baseline (660.617 us; speedup 1.0000x reference)
//
#include <hip/hip_runtime.h>
#include <hip/hip_bf16.h>

// sLSTM block, MI355X. Strategy: one fused bf16 MFMA GEMM
//   P[g] = [x|h] (4096x4096) @ [Wg|Rg]^T (2048x4096), g in {z,i,f,o}
// with the gating epilogue fused in (LDS exchange of the 4 gate tiles).
// ws layout: A_bf16 [4096][4096] @0 (32MB) | Wb_bf16 [4][2048][4096] @32MB (64MB)
//            | Bb fp32 [4][2048] @96MB.

#define BATCH 4096
#define NHID  2048
#define KDIM  4096
#define NTOT  8388608L  // BATCH*NHID

typedef float  f32x4  __attribute__((ext_vector_type(4)));
typedef short  short8 __attribute__((ext_vector_type(8)));

#define GL_LDS16(gp, lp)                                                      \
    __builtin_amdgcn_global_load_lds(                                         \
        (const __attribute__((address_space(1))) void*)(gp),                  \
        (__attribute__((address_space(3))) void*)(lp), 16, 0, 0)

__device__ __forceinline__ unsigned short f2bf(float f) {
    unsigned u = __float_as_uint(f);
    unsigned r = (u + 0x7fffu + ((u >> 16) & 1u)) >> 16;   // RNE
    return (unsigned short)r;
}

// ---- fp32 -> bf16 pack of A = [x | h_prev], 4096 x 4096 -------------------
__global__ void convA_kernel(const float* __restrict__ x,
                             const float* __restrict__ h,
                             unsigned short* __restrict__ A) {
    int gid = blockIdx.x * 256 + threadIdx.x;       // 4096*1024 groups of 4
    int row = gid >> 10;
    int col = (gid & 1023) << 2;
    const float* src = (col < 2048) ? (x + (long)row * 2048 + col)
                                    : (h + (long)row * 2048 + (col - 2048));
    float4 v = *(const float4*)src;
    ushort4 o;
    o.x = f2bf(v.x); o.y = f2bf(v.y); o.z = f2bf(v.z); o.w = f2bf(v.w);
    *(ushort4*)(A + ((long)row << 12) + col) = o;
}

// ---- fp32 -> bf16 pack of Wb[g][j][k] (k<2048: Wg, k>=2048: Rg) -----------
__global__ void convW_kernel(const float* __restrict__ w0, const float* __restrict__ w1,
                             const float* __restrict__ w2, const float* __restrict__ w3,
                             const float* __restrict__ w4, const float* __restrict__ w5,
                             const float* __restrict__ w6, const float* __restrict__ w7,
                             unsigned short* __restrict__ Wb) {
    int z = blockIdx.y;                              // 0..3 = Wzx..Wox, 4..7 = Rzh..Roh
    const float* src;
    switch (z) {
        case 0: src = w0; break; case 1: src = w1; break;
        case 2: src = w2; break; case 3: src = w3; break;
        case 4: src = w4; break; case 5: src = w5; break;
        case 6: src = w6; break; default: src = w7; break;
    }
    int gid = blockIdx.x * 256 + threadIdx.x;        // 2048*512 groups of 4
    int row = gid >> 9;
    int col = (gid & 511) << 2;
    float4 v = *(const float4*)(src + (long)row * 2048 + col);
    ushort4 o;
    o.x = f2bf(v.x); o.y = f2bf(v.y); o.z = f2bf(v.z); o.w = f2bf(v.w);
    int g = z & 3, hf = z >> 2;
    *(ushort4*)(Wb + (long)g * NHID * KDIM + (long)row * KDIM + hf * 2048 + col) = o;
}

// ---- combined bias Bb[g][j] = Wg_b[j] + Rg_b[j] ---------------------------
__global__ void bias_kernel(const float* __restrict__ b0, const float* __restrict__ b1,
                            const float* __restrict__ b2, const float* __restrict__ b3,
                            const float* __restrict__ r0, const float* __restrict__ r1,
                            const float* __restrict__ r2, const float* __restrict__ r3,
                            float* __restrict__ Bb) {
    int gid = blockIdx.x * 256 + threadIdx.x;        // 0..8191
    int g = gid >> 11, j = gid & 2047;
    const float *wb, *rb;
    switch (g) {
        case 0: wb = b0; rb = r0; break; case 1: wb = b1; rb = r1; break;
        case 2: wb = b2; rb = r2; break; default: wb = b3; rb = r3; break;
    }
    Bb[gid] = wb[j] + rb[j];
}

// ---- fused GEMM (4 gates) + sLSTM epilogue --------------------------------
// block: 256 threads = 4 waves, wave g computes gate g's 64x64 tile.
// grid: (64 row-tiles, 32 col-tiles); x fastest -> concurrent blocks share W-slice.
// LDS: As [64 rows][8 chunks of 16B] @0 (8KB), Bs [4][64][8 chunks] @8KB (32KB).
// XOR swizzle: LDS chunk (r, jj) holds global k-chunk jj^(r&7)  (conflict-free reads).
__global__ __launch_bounds__(256, 3) void slstm_kernel(
    const __hip_bfloat16* __restrict__ A,    // [4096][4096]
    const __hip_bfloat16* __restrict__ W,    // [4][2048][4096]
    const float* __restrict__ Bb,            // [4][2048]
    const float* __restrict__ c_prev,
    const float* __restrict__ n_prev,
    const float* __restrict__ m_prev,
    float* __restrict__ out)                 // h | c | n | m
{
    __shared__ uint4 smem4[40960 / 16];
    char* smem = (char*)smem4;

    const int tid  = threadIdx.x;
    const int lane = tid & 63;
    const int wv   = tid >> 6;     // gate id
    const int lm   = lane & 15;
    const int quad = lane >> 4;
    const int l7   = lm & 7;

    const int row0 = blockIdx.x * 64;   // batch rows
    const int col0 = blockIdx.y * 64;   // hidden cols

    // staging address precompute (element offsets; advance by k0 per iter)
    int gofsA[2]; char* ldsA[2];
#pragma unroll
    for (int t = 0; t < 2; ++t) {
        int idx = (wv * 2 + t) * 64 + lane;          // 0..511 (chunk id)
        int r = idx >> 3, jj = idx & 7;
        int j = jj ^ (r & 7);
        gofsA[t] = (row0 + r) * KDIM + j * 8;
        ldsA[t]  = smem + (wv * 2 + t) * 1024;
    }
    int gofsB[8]; char* ldsB[8];
#pragma unroll
    for (int t = 0; t < 8; ++t) {
        int idx = (wv * 8 + t) * 64 + lane;          // 0..2047
        int g = idx >> 9, rr = (idx >> 3) & 63, jj = idx & 7;
        int j = jj ^ (rr & 7);
        gofsB[t] = (g * NHID + col0 + rr) * KDIM + j * 8;
        ldsB[t]  = smem + 8192 + (wv * 8 + t) * 1024;
    }

    f32x4 acc[4][4];
#pragma unroll
    for (int mt = 0; mt < 4; ++mt)
#pragma unroll
        for (int nt = 0; nt < 4; ++nt)
#pragma unroll
            for (int r = 0; r < 4; ++r) acc[mt][nt][r] = 0.0f;

    for (int kt = 0; kt < KDIM / 64; ++kt) {
        const int k0 = kt * 64;
        __syncthreads();
#pragma unroll
        for (int t = 0; t < 2; ++t) GL_LDS16(A + gofsA[t] + k0, ldsA[t]);
#pragma unroll
        for (int t = 0; t < 8; ++t) GL_LDS16(W + gofsB[t] + k0, ldsB[t]);
        __syncthreads();
#pragma unroll
        for (int kk = 0; kk < 2; ++kk) {
            const int cof = ((kk * 4 + quad) ^ l7) * 16;
            short8 af[4], bf[4];
#pragma unroll
            for (int mt = 0; mt < 4; ++mt)
                af[mt] = *(const short8*)(smem + (mt * 16 + lm) * 128 + cof);
#pragma unroll
            for (int nt = 0; nt < 4; ++nt)
                bf[nt] = *(const short8*)(smem + 8192 + wv * 8192 + (nt * 16 + lm) * 128 + cof);
#pragma unroll
            for (int mt = 0; mt < 4; ++mt)
#pragma unroll
                for (int nt = 0; nt < 4; ++nt)
                    acc[mt][nt] = __builtin_amdgcn_mfma_f32_16x16x32_bf16(
                        af[mt], bf[nt], acc[mt][nt], 0, 0, 0);
        }
    }

    // ---- epilogue: exchange gate tiles through LDS, compute h,c,n,m ----
    float* exch = (float*)smem;   // [4 gates][16 rows][65] floats (padded)
#pragma unroll
    for (int mt = 0; mt < 4; ++mt) {
        __syncthreads();          // staging/exch LDS free to overwrite
#pragma unroll
        for (int nt = 0; nt < 4; ++nt)
#pragma unroll
            for (int r = 0; r < 4; ++r)
                exch[(wv * 16 + quad * 4 + r) * 65 + nt * 16 + lm] = acc[mt][nt][r];
        __syncthreads();
#pragma unroll
        for (int q = 0; q < 4; ++q) {
            int e   = q * 256 + tid;          // 0..1023
            int row = e >> 6, col = e & 63;
            int R = row0 + mt * 16 + row;
            int C = col0 + col;
            long idx = (long)R * NHID + C;
            float zp = exch[(0 * 16 + row) * 65 + col] + Bb[C];
            float ip = exch[(1 * 16 + row) * 65 + col] + Bb[2048 + C];
            float fp = exch[(2 * 16 + row) * 65 + col] + Bb[4096 + C];
            float op = exch[(3 * 16 + row) * 65 + col] + Bb[6144 + C];
            float cp = c_prev[idx], np = n_prev[idx], mp = m_prev[idx];
            float z  = tanhf(zp);
            float o  = 1.0f / (1.0f + __expf(-op));
            float mm = fmaxf(fp + mp, ip);
            float ih = __expf(ip - mm);
            float fh = __expf(fp + mp - mm);
            float cc = fh * cp + ih * z;
            float nn = fh * np + ih;
            float hh = o * cc / nn;
            out[idx]            = hh;
            out[NTOT + idx]     = cc;
            out[2 * NTOT + idx] = nn;
            out[3 * NTOT + idx] = mm;
        }
    }
}

extern "C" void kernel_launch(void* const* d_in, const int* in_sizes, int n_in,
                              void* d_out, int out_size, void* d_ws, size_t ws_size,
                              hipStream_t stream) {
    const float* x      = (const float*)d_in[0];
    const float* h_prev = (const float*)d_in[1];
    const float* c_prev = (const float*)d_in[2];
    const float* n_prev = (const float*)d_in[3];
    const float* m_prev = (const float*)d_in[4];
    // weights: d_in[5+2g]=Wg_w, d_in[6+2g]=Wg_b, d_in[13+2g]=Rg_w, d_in[14+2g]=Rg_b
    unsigned short* A  = (unsigned short*)d_ws;                          // 32 MB
    unsigned short* Wb = (unsigned short*)((char*)d_ws + 33554432);      // 64 MB
    float*          Bb = (float*)((char*)d_ws + 100663296);              // 32 KB

    convA_kernel<<<16384, 256, 0, stream>>>(x, h_prev, A);
    convW_kernel<<<dim3(4096, 8), 256, 0, stream>>>(
        (const float*)d_in[5], (const float*)d_in[7], (const float*)d_in[9],
        (const float*)d_in[11], (const float*)d_in[13], (const float*)d_in[15],
        (const float*)d_in[17], (const float*)d_in[19], Wb);
    bias_kernel<<<32, 256, 0, stream>>>(
        (const float*)d_in[6], (const float*)d_in[8], (const float*)d_in[10],
        (const float*)d_in[12], (const float*)d_in[14], (const float*)d_in[16],
        (const float*)d_in[18], (const float*)d_in[20], Bb);

    slstm_kernel<<<dim3(64, 32), 256, 0, stream>>>(
        (const __hip_bfloat16*)A, (const __hip_bfloat16*)Wb, Bb,
        c_prev, n_prev, m_prev, (float*)d_out);
}

// Round 4
// 582.008 us; speedup vs baseline: 1.1351x; 1.1351x over previous
//
#include <hip/hip_runtime.h>
#include <hip/hip_bf16.h>

// sLSTM block, MI355X. One fused bf16 MFMA GEMM
//   P[g] = [x|h] (4096x4096) @ [Wg|Rg]^T (2048x4096), g in {z,i,f,o}
// with gating epilogue fused (LDS exchange of the 4 gate tiles).
// R2: 512-thread blocks, 128 rows x 64 cols x 4 gates, BK=64 (256 MFMA/barrier,
// target 2 blocks/CU = 50% occ), nontemporal state loads / output stores.
// R3 FIX: merged staging loop must add the A->W element distance (16777216)
// for W-tile loads — A and W are contiguous in ws so one base pointer works.
// ws: A_bf16 [4096][4096] @0 (32MB) | Wb_bf16 [4][2048][4096] @32MB (64MB)
//     | Bb fp32 [4][2048] @96MB.

#define BATCH 4096
#define NHID  2048
#define KDIM  4096
#define NTOT  8388608L   // BATCH*NHID
#define AW_OFS 16777216  // elements from A base to W base in ws

typedef float  f32x4   __attribute__((ext_vector_type(4)));
typedef short  short8  __attribute__((ext_vector_type(8)));
typedef unsigned short ushort8 __attribute__((ext_vector_type(8)));

#define GL_LDS16(gp, lp)                                                      \
    __builtin_amdgcn_global_load_lds(                                         \
        (const __attribute__((address_space(1))) void*)(gp),                  \
        (__attribute__((address_space(3))) void*)(lp), 16, 0, 0)

__device__ __forceinline__ unsigned short f2bf(float f) {
    unsigned u = __float_as_uint(f);
    unsigned r = (u + 0x7fffu + ((u >> 16) & 1u)) >> 16;   // RNE
    return (unsigned short)r;
}

// ---- fp32 -> bf16 pack of A = [x | h_prev], 4096 x 4096 -------------------
__global__ void convA_kernel(const float* __restrict__ x,
                             const float* __restrict__ h,
                             unsigned short* __restrict__ A) {
    int gid = blockIdx.x * 256 + threadIdx.x;       // 4096*512 groups of 8
    int row = gid >> 9;
    int col = (gid & 511) << 3;
    const float* src = (col < 2048) ? (x + (long)row * 2048 + col)
                                    : (h + (long)row * 2048 + (col - 2048));
    f32x4 v0 = __builtin_nontemporal_load((const f32x4*)src);
    f32x4 v1 = __builtin_nontemporal_load((const f32x4*)src + 1);
    ushort8 o;
    o[0] = f2bf(v0[0]); o[1] = f2bf(v0[1]); o[2] = f2bf(v0[2]); o[3] = f2bf(v0[3]);
    o[4] = f2bf(v1[0]); o[5] = f2bf(v1[1]); o[6] = f2bf(v1[2]); o[7] = f2bf(v1[3]);
    *(ushort8*)(A + ((long)row << 12) + col) = o;
}

// ---- fp32 -> bf16 pack of Wb[g][j][k] (k<2048: Wg, k>=2048: Rg) -----------
__global__ void convW_kernel(const float* __restrict__ w0, const float* __restrict__ w1,
                             const float* __restrict__ w2, const float* __restrict__ w3,
                             const float* __restrict__ w4, const float* __restrict__ w5,
                             const float* __restrict__ w6, const float* __restrict__ w7,
                             unsigned short* __restrict__ Wb) {
    int z = blockIdx.y;                              // 0..3 = Wzx..Wox, 4..7 = Rzh..Roh
    const float* src;
    switch (z) {
        case 0: src = w0; break; case 1: src = w1; break;
        case 2: src = w2; break; case 3: src = w3; break;
        case 4: src = w4; break; case 5: src = w5; break;
        case 6: src = w6; break; default: src = w7; break;
    }
    int gid = blockIdx.x * 256 + threadIdx.x;        // 2048*256 groups of 8
    int row = gid >> 8;
    int col = (gid & 255) << 3;
    const float* p = src + (long)row * 2048 + col;
    f32x4 v0 = __builtin_nontemporal_load((const f32x4*)p);
    f32x4 v1 = __builtin_nontemporal_load((const f32x4*)p + 1);
    ushort8 o;
    o[0] = f2bf(v0[0]); o[1] = f2bf(v0[1]); o[2] = f2bf(v0[2]); o[3] = f2bf(v0[3]);
    o[4] = f2bf(v1[0]); o[5] = f2bf(v1[1]); o[6] = f2bf(v1[2]); o[7] = f2bf(v1[3]);
    int g = z & 3, hf = z >> 2;
    *(ushort8*)(Wb + (long)g * NHID * KDIM + (long)row * KDIM + hf * 2048 + col) = o;
}

// ---- combined bias Bb[g][j] = Wg_b[j] + Rg_b[j] ---------------------------
__global__ void bias_kernel(const float* __restrict__ b0, const float* __restrict__ b1,
                            const float* __restrict__ b2, const float* __restrict__ b3,
                            const float* __restrict__ r0, const float* __restrict__ r1,
                            const float* __restrict__ r2, const float* __restrict__ r3,
                            float* __restrict__ Bb) {
    int gid = blockIdx.x * 256 + threadIdx.x;        // 0..8191
    int g = gid >> 11, j = gid & 2047;
    const float *wb, *rb;
    switch (g) {
        case 0: wb = b0; rb = r0; break; case 1: wb = b1; rb = r1; break;
        case 2: wb = b2; rb = r2; break; default: wb = b3; rb = r3; break;
    }
    Bb[gid] = wb[j] + rb[j];
}

// ---- fused GEMM (4 gates) + sLSTM epilogue --------------------------------
// block: 512 threads = 8 waves; wave w: gate = w&3, rowhalf = w>>2.
// Each wave computes a 64x64 tile of its gate (4x4 of 16x16x32 MFMA).
// grid: (32 row-tiles of 128, 32 col-tiles of 64); x fastest (W-slice L2 share).
// LDS staging 48KB: A [128 rows][8 x 16B] @0 (16KB), B [4][64][8 x 16B] @16KB.
// XOR swizzle: chunk (r, jj) holds k-chunk jj^(r&7)  (conflict-free ds_read_b128).
__global__ __launch_bounds__(512, 4) void slstm_kernel(
    const __hip_bfloat16* __restrict__ A,    // [4096][4096], W follows at +AW_OFS
    const float* __restrict__ Bb,            // [4][2048]
    const float* __restrict__ c_prev,
    const float* __restrict__ n_prev,
    const float* __restrict__ m_prev,
    float* __restrict__ out)                 // h | c | n | m
{
    __shared__ uint4 smem4[49152 / 16];
    char* smem = (char*)smem4;

    const int tid  = threadIdx.x;
    const int lane = tid & 63;
    const int wv   = tid >> 6;     // wave id 0..7
    const int gate = wv & 3;
    const int rh   = wv >> 2;      // row half 0/1
    const int lm   = lane & 15;
    const int quad = lane >> 4;
    const int l7   = lm & 7;

    const int row0 = blockIdx.x * 128;  // batch rows
    const int col0 = blockIdx.y * 64;   // hidden cols

    // staging: 48 loads of 1KB (64 lanes x 16B); wave w issues ids w*6..w*6+5.
    // ids 0..15 -> A tile (128 x 64), ids 16..47 -> B tiles (4 x 64 x 64).
    int gofs[6]; char* lds[6];
#pragma unroll
    for (int t = 0; t < 6; ++t) {
        int id = wv * 6 + t;
        if (id < 16) {
            int idx = id * 64 + lane;                // 0..1023
            int r = idx >> 3, jj = idx & 7;
            int j = jj ^ (r & 7);
            gofs[t] = (row0 + r) * KDIM + j * 8;
            lds[t]  = smem + id * 1024;
        } else {
            int idx = (id - 16) * 64 + lane;         // 0..2047
            int g = idx >> 9, rr = (idx >> 3) & 63, jj = idx & 7;
            int j = jj ^ (rr & 7);
            gofs[t] = AW_OFS + (g * NHID + col0 + rr) * KDIM + j * 8;  // R3 FIX
            lds[t]  = smem + 16384 + (id - 16) * 1024;
        }
    }

    f32x4 acc[4][4];
#pragma unroll
    for (int mt = 0; mt < 4; ++mt)
#pragma unroll
        for (int nt = 0; nt < 4; ++nt)
#pragma unroll
            for (int r = 0; r < 4; ++r) acc[mt][nt][r] = 0.0f;

    const char* aB = smem + rh * 8192;                 // rowhalf A base
    const char* bB = smem + 16384 + gate * 8192;       // gate B base

    for (int kt = 0; kt < KDIM / 64; ++kt) {
        const int k0 = kt * 64;
        __syncthreads();
#pragma unroll
        for (int t = 0; t < 6; ++t) GL_LDS16(A + gofs[t] + k0, lds[t]);
        __syncthreads();
#pragma unroll
        for (int kk = 0; kk < 2; ++kk) {
            const int cof = ((kk * 4 + quad) ^ l7) * 16;
            short8 af[4], bf[4];
#pragma unroll
            for (int mt = 0; mt < 4; ++mt)
                af[mt] = *(const short8*)(aB + (mt * 16 + lm) * 128 + cof);
#pragma unroll
            for (int nt = 0; nt < 4; ++nt)
                bf[nt] = *(const short8*)(bB + (nt * 16 + lm) * 128 + cof);
#pragma unroll
            for (int mt = 0; mt < 4; ++mt)
#pragma unroll
                for (int nt = 0; nt < 4; ++nt)
                    acc[mt][nt] = __builtin_amdgcn_mfma_f32_16x16x32_bf16(
                        af[mt], bf[nt], acc[mt][nt], 0, 0, 0);
        }
    }

    // ---- epilogue: exchange gate tiles through LDS, compute h,c,n,m ----
    float* exch = (float*)smem;   // [2 rh][4 gates][16 rows][65] floats (33.3KB)
#pragma unroll
    for (int mt = 0; mt < 4; ++mt) {
        __syncthreads();
#pragma unroll
        for (int nt = 0; nt < 4; ++nt)
#pragma unroll
            for (int r = 0; r < 4; ++r)
                exch[((rh * 4 + gate) * 16 + quad * 4 + r) * 65 + nt * 16 + lm] =
                    acc[mt][nt][r];
        __syncthreads();
#pragma unroll
        for (int q = 0; q < 4; ++q) {
            int e   = q * 512 + tid;          // 0..2047
            int erh = e >> 10, row = (e >> 6) & 15, col = e & 63;
            int R = row0 + erh * 64 + mt * 16 + row;
            int C = col0 + col;
            long idx = (long)R * NHID + C;
            float zp = exch[((erh * 4 + 0) * 16 + row) * 65 + col] + Bb[C];
            float ip = exch[((erh * 4 + 1) * 16 + row) * 65 + col] + Bb[2048 + C];
            float fp = exch[((erh * 4 + 2) * 16 + row) * 65 + col] + Bb[4096 + C];
            float op = exch[((erh * 4 + 3) * 16 + row) * 65 + col] + Bb[6144 + C];
            float cp = __builtin_nontemporal_load(c_prev + idx);
            float np = __builtin_nontemporal_load(n_prev + idx);
            float mp = __builtin_nontemporal_load(m_prev + idx);
            float z  = tanhf(zp);
            float o  = 1.0f / (1.0f + __expf(-op));
            float mm = fmaxf(fp + mp, ip);
            float ih = __expf(ip - mm);
            float fh = __expf(fp + mp - mm);
            float cc = fh * cp + ih * z;
            float nn = fh * np + ih;
            float hh = o * cc / nn;
            __builtin_nontemporal_store(hh, out + idx);
            __builtin_nontemporal_store(cc, out + NTOT + idx);
            __builtin_nontemporal_store(nn, out + 2 * NTOT + idx);
            __builtin_nontemporal_store(mm, out + 3 * NTOT + idx);
        }
    }
}

extern "C" void kernel_launch(void* const* d_in, const int* in_sizes, int n_in,
                              void* d_out, int out_size, void* d_ws, size_t ws_size,
                              hipStream_t stream) {
    const float* x      = (const float*)d_in[0];
    const float* h_prev = (const float*)d_in[1];
    const float* c_prev = (const float*)d_in[2];
    const float* n_prev = (const float*)d_in[3];
    const float* m_prev = (const float*)d_in[4];
    unsigned short* A  = (unsigned short*)d_ws;                          // 32 MB
    unsigned short* Wb = (unsigned short*)((char*)d_ws + 33554432);      // 64 MB
    float*          Bb = (float*)((char*)d_ws + 100663296);              // 32 KB

    convA_kernel<<<8192, 256, 0, stream>>>(x, h_prev, A);
    convW_kernel<<<dim3(2048, 8), 256, 0, stream>>>(
        (const float*)d_in[5], (const float*)d_in[7], (const float*)d_in[9],
        (const float*)d_in[11], (const float*)d_in[13], (const float*)d_in[15],
        (const float*)d_in[17], (const float*)d_in[19], Wb);
    bias_kernel<<<32, 256, 0, stream>>>(
        (const float*)d_in[6], (const float*)d_in[8], (const float*)d_in[10],
        (const float*)d_in[12], (const float*)d_in[14], (const float*)d_in[16],
        (const float*)d_in[18], (const float*)d_in[20], Bb);

    slstm_kernel<<<dim3(32, 32), 512, 0, stream>>>(
        (const __hip_bfloat16*)A, Bb, c_prev, n_prev, m_prev, (float*)d_out);
}